// Round 27
// baseline (150.975 us; speedup 1.0000x reference)
//
#include <hip/hip_runtime.h>
#include <hip/hip_bf16.h>
#include <math.h>

// DeformableAttention2D — round 27: eliminate ALL weight transposes.
// k2/k4 now read weights row-major per-thread via float4 (the G13 16B/lane
// pattern k1 already uses). kprep shrinks 1792 -> 576 blocks (table + kx/vx
// only); WqT/mowT/owT/qwT/kwT/vwT buffers deleted. FMA order bit-identical
// to round 26 (124.1us, absmax 4.88e-4).
// Sizes (fixed): B=4, N=256, DIM=256, HEADS=8, GROUPS=8, INNER=512, DH=64.

#define DIMC 256
#define NQ 256
#define HEADS 8
#define GROUPS 8
#define INNER 512
#define DH 64
#define HDX 32
#define HWT 16
#define TS 256
#define UMAXC 1.2995f

typedef unsigned short ushort_t;

__device__ __forceinline__ float gelu_exact(float x) {
    return 0.5f * x * (1.f + erff(x * 0.70710678118654752f));
}
__device__ __forceinline__ float samp4(const float* __restrict__ img, int yi, int xi) {
    bool valid = (xi >= 0) && (xi < 4) && (yi >= 0) && (yi < 4);
    int idx = min(max(yi, 0), 3) * 4 + min(max(xi, 0), 3);
    return valid ? img[idx] : 0.f;
}
__device__ __forceinline__ float tab_lookup(const float* __restrict__ tab,
                                            float px, float py) {
    const float SCL = (float)(TS - 1) / (2.f * UMAXC);
    float u = copysignf(__logf(1.f + fabsf(px)), px);
    float v = copysignf(__logf(1.f + fabsf(py)), py);
    float fx = fminf(fmaxf((u + UMAXC) * SCL, 0.f), (float)(TS - 1) - 1e-3f);
    float fy = fminf(fmaxf((v + UMAXC) * SCL, 0.f), (float)(TS - 1) - 1e-3f);
    int ix = (int)fx, iy = (int)fy;
    float ax = fx - ix, ay = fy - iy;
    const float* r0 = tab + iy * TS + ix;
    float t00 = r0[0], t01 = r0[1], t10 = r0[TS], t11 = r0[TS + 1];
    float t0 = fmaf(ax, t01 - t00, t00);
    float t1 = fmaf(ax, t11 - t10, t10);
    return fmaf(ay, t1 - t0, t0);
}

// ---------------- KPREP: k3t table (0..511) | k1 kx/vx (512..575) ----------------
__global__ __launch_bounds__(256) void kprep(
        const float* __restrict__ in_w,
        const float* __restrict__ w0, const float* __restrict__ b0,
        const float* __restrict__ b1, const float* __restrict__ w1,
        const float* __restrict__ w2, const float* __restrict__ b2,
        const float* __restrict__ rgb, const float* __restrict__ in_b,
        float* __restrict__ tab,
        float* __restrict__ kx, float* __restrict__ vx) {
    __shared__ float w1_s[64][64];
    __shared__ float w0a_s[64], w0b_s[64], b0_s[64];
    __shared__ float2 b1w2_s[64];
    __shared__ __align__(16) float kvin[DIMC];
    int bid = blockIdx.x;
    int tid = threadIdx.x;

    if (bid < 512) {
        // ---- k3t: CPB table build (2 lanes per entry) ----
        for (int r = 0; r < 16; ++r) {
            int idx = r * 256 + tid;
            w1_s[idx >> 6][idx & 63] = w1[idx];
        }
        if (tid < 64) {
            w0a_s[tid] = w0[2 * tid];
            w0b_s[tid] = w0[2 * tid + 1];
            b0_s[tid] = b0[tid];
            float2 bw; bw.x = b1[tid]; bw.y = w2[tid];
            b1w2_s[tid] = bw;
        }
        __syncthreads();

        int gid = bid * 256 + tid;              // 0..131071
        int entry = gid >> 1;
        int half = gid & 1;
        int ty = entry >> 8, tx = entry & (TS - 1);
        const float step = 2.f * UMAXC / (float)(TS - 1);
        float u = fmaf((float)tx, step, -UMAXC);
        float v = fmaf((float)ty, step, -UMAXC);

        float h0[64];
        #pragma unroll
        for (int c = 0; c < 64; ++c)
            h0[c] = fmaxf(fmaf(w0a_s[c], u, fmaf(w0b_s[c], v, b0_s[c])), 0.f);
        float acc = half ? 0.f : b2[0];
        int c2base = half * 32;
        #pragma unroll 1
        for (int c2o = 0; c2o < 32; c2o += 2) {
            int c2 = c2base + c2o;
            float sA0 = 0.f, sA1 = 0.f, sB0 = 0.f, sB1 = 0.f;
            const float* wA = &w1_s[c2][0];
            const float* wB = &w1_s[c2 + 1][0];
            #pragma unroll
            for (int k = 0; k < 64; k += 2) {
                sA0 = fmaf(wA[k], h0[k], sA0);
                sA1 = fmaf(wA[k + 1], h0[k + 1], sA1);
                sB0 = fmaf(wB[k], h0[k], sB0);
                sB1 = fmaf(wB[k + 1], h0[k + 1], sB1);
            }
            float2 bwA = b1w2_s[c2], bwB = b1w2_s[c2 + 1];
            acc += fmaxf(sA0 + sA1 + bwA.x, 0.f) * bwA.y;
            acc += fmaxf(sB0 + sB1 + bwB.x, 0.f) * bwB.y;
        }
        acc += __shfl_xor(acc, 1, 64);
        if (half == 0) tab[ty * TS + tx] = acc;
    } else {
        // ---- k1: kx, vx ----
        int bb = bid - 512;
        int b = bb >> 4;
        int tt = bb & 15;
        int c = tid;
        float ang = (float)tt * powf(10000.f, -(float)(c >> 1) * (1.f / 128.f));
        float sv = (c & 1) ? cosf(ang) : sinf(ang);
        kvin[c] = rgb[(b * DIMC + c) * HWT + tt] + sv;
        __syncthreads();
        const float4* x4 = (const float4*)kvin;
        const float4* wk4 = (const float4*)(in_w + (DIMC + c) * DIMC);
        const float4* wv4 = (const float4*)(in_w + (2 * DIMC + c) * DIMC);
        float ak0 = in_b[DIMC + c], ak1 = 0.f, av0 = in_b[2 * DIMC + c], av1 = 0.f;
        #pragma unroll 4
        for (int d4 = 0; d4 < 64; ++d4) {
            float4 x = x4[d4], wk = wk4[d4], wv = wv4[d4];
            ak0 = fmaf(wk.x, x.x, ak0); ak1 = fmaf(wk.y, x.y, ak1);
            ak0 = fmaf(wk.z, x.z, ak0); ak1 = fmaf(wk.w, x.w, ak1);
            av0 = fmaf(wv.x, x.x, av0); av1 = fmaf(wv.y, x.y, av1);
            av0 = fmaf(wv.z, x.z, av0); av1 = fmaf(wv.w, x.w, av1);
        }
        kx[(b * HWT + tt) * DIMC + c] = ak0 + ak1;
        vx[(b * HWT + tt) * DIMC + c] = av0 + av1;
    }
}

// ---------------- K2: 2 rows per block (grid 512), row-major weights ----------------
__global__ __launch_bounds__(256) void k2_qkv(
        const float* __restrict__ pose_feat, const float* __restrict__ rgb,
        const float* __restrict__ pose_init, const float* __restrict__ in_b,
        const float* __restrict__ in_w, const float* __restrict__ mow,
        const float* __restrict__ mob, const float* __restrict__ pe_gauss,
        const float* __restrict__ off_w1, const float* __restrict__ off_b1,
        const float* __restrict__ off_w2,
        const float* __restrict__ q_w, const float* __restrict__ k_w,
        const float* __restrict__ v_w,
        const float* __restrict__ kx, const float* __restrict__ vx,
        float* __restrict__ qT, float* __restrict__ kTt, float* __restrict__ vT,
        float* __restrict__ vgrid_g) {
    int b = blockIdx.x >> 7;
    int n0 = (blockIdx.x & 127) * 2;
    int t = threadIdx.x;
    __shared__ __align__(16) float xs[2][DIMC];
    __shared__ __align__(16) float qxs[2][DIMC];
    __shared__ __align__(16) float ctx[2][DIMC];
    __shared__ __align__(16) float x2[2][DIMC];
    __shared__ float lg[2][128], psm[2][128];
    __shared__ float qls[2][INNER];
    __shared__ float kvs[2][DIMC];
    __shared__ float vg[2][GROUPS][2];
    __shared__ float g01[2][2];

    if (t < 4) {
        int r = t >> 1, comp = t & 1;
        g01[r][comp] = 2.f * pose_init[(b * 2 + comp) * NQ + n0 + r] - 1.f;
    }
    float2 pf2 = *(const float2*)(pose_feat + (b * DIMC + t) * NQ + n0);
    float pfv[2] = {pf2.x, pf2.y};
    __syncthreads();
    {
        int j = t & 127;
        float pj0 = pe_gauss[j], pj1 = pe_gauss[128 + j];
        #pragma unroll
        for (int r = 0; r < 2; ++r) {
            float cc = (g01[r][0] * pj0 + g01[r][1] * pj1) * 6.28318530717958648f;
            float sc = (t < 128) ? sinf(cc) : cosf(cc);
            xs[r][t] = pfv[r] + sc;
        }
    }
    __syncthreads();
    {
        // qx[t] = in_b[t] + sum_d in_w[t*256+d] * xs[d]  (row-major float4)
        float bq = in_b[t];
        float a0 = bq, a1 = bq;
        const float4* wq4 = (const float4*)(in_w + t * DIMC);
        const float4* xs0 = (const float4*)&xs[0][0];
        const float4* xs1 = (const float4*)&xs[1][0];
        #pragma unroll 4
        for (int d4 = 0; d4 < 64; ++d4) {
            float4 w = wq4[d4];
            float4 x0 = xs0[d4], x1 = xs1[d4];
            a0 = fmaf(w.x, x0.x, a0); a0 = fmaf(w.y, x0.y, a0); a0 = fmaf(w.z, x0.z, a0); a0 = fmaf(w.w, x0.w, a0);
            a1 = fmaf(w.x, x1.x, a1); a1 = fmaf(w.y, x1.y, a1); a1 = fmaf(w.z, x1.z, a1); a1 = fmaf(w.w, x1.w, a1);
        }
        qxs[0][t] = a0; qxs[1][t] = a1;
    }
    __syncthreads();
    {
        int r = t >> 7, hh = (t >> 4) & 7, tt = t & 15;
        const float4* kp = (const float4*)(kx + (b * HWT + tt) * DIMC + hh * HDX);
        const float4* qp = (const float4*)(&qxs[r][hh * HDX]);
        float a = 0.f;
        #pragma unroll
        for (int d4 = 0; d4 < 8; ++d4) {
            float4 k4 = kp[d4], q4 = qp[d4];
            a = fmaf(q4.x, k4.x, a); a = fmaf(q4.y, k4.y, a);
            a = fmaf(q4.z, k4.z, a); a = fmaf(q4.w, k4.w, a);
        }
        lg[r][hh * 16 + tt] = a * 0.17677669529663689f;
    }
    __syncthreads();
    if (t < 16) {
        int r = t >> 3, hh = t & 7;
        float m = -1e30f;
        for (int tt = 0; tt < 16; ++tt) m = fmaxf(m, lg[r][hh * 16 + tt]);
        float s = 0.f;
        for (int tt = 0; tt < 16; ++tt) {
            float e = __expf(lg[r][hh * 16 + tt] - m);
            psm[r][hh * 16 + tt] = e; s += e;
        }
        float rr = 1.f / s;
        for (int tt = 0; tt < 16; ++tt) psm[r][hh * 16 + tt] *= rr;
    }
    __syncthreads();
    {
        int hh = t >> 5;
        const float* vp = vx + b * HWT * DIMC + t;
        float a0 = 0.f, a1 = 0.f;
        #pragma unroll
        for (int tt = 0; tt < 16; ++tt) {
            float vv = vp[tt * DIMC];
            a0 = fmaf(psm[0][hh * 16 + tt], vv, a0);
            a1 = fmaf(psm[1][hh * 16 + tt], vv, a1);
        }
        ctx[0][t] = a0; ctx[1][t] = a1;
    }
    __syncthreads();
    {
        // pose_cross[t] = mob[t] + sum_d mow[t*256+d] * ctx[d]
        float bm = mob[t];
        float a0 = bm, a1 = bm;
        const float4* wm4 = (const float4*)(mow + t * DIMC);
        const float4* c04 = (const float4*)&ctx[0][0];
        const float4* c14 = (const float4*)&ctx[1][0];
        #pragma unroll 4
        for (int d4 = 0; d4 < 64; ++d4) {
            float4 w = wm4[d4];
            float4 c0 = c04[d4], c1 = c14[d4];
            a0 = fmaf(w.x, c0.x, a0); a0 = fmaf(w.y, c0.y, a0); a0 = fmaf(w.z, c0.z, a0); a0 = fmaf(w.w, c0.w, a0);
            a1 = fmaf(w.x, c1.x, a1); a1 = fmaf(w.y, c1.y, a1); a1 = fmaf(w.z, c1.z, a1); a1 = fmaf(w.w, c1.w, a1);
        }
        x2[0][t] = pfv[0] + a0; x2[1][t] = pfv[1] + a1;
    }
    __syncthreads();
    #pragma unroll
    for (int rep = 0; rep < 2; ++rep) {
        int ch = rep * 256 + t;
        int g = ch >> 6;
        const float4* qw4 = (const float4*)(q_w + ch * 32);
        const float4* xa4 = (const float4*)&x2[0][g * 32];
        const float4* xb4 = (const float4*)&x2[1][g * 32];
        float aq0 = 0.f, aq1 = 0.f;
        #pragma unroll
        for (int c4 = 0; c4 < 8; ++c4) {
            float4 w = qw4[c4];
            float4 xa = xa4[c4], xb = xb4[c4];
            aq0 = fmaf(w.x, xa.x, aq0); aq0 = fmaf(w.y, xa.y, aq0); aq0 = fmaf(w.z, xa.z, aq0); aq0 = fmaf(w.w, xa.w, aq0);
            aq1 = fmaf(w.x, xb.x, aq1); aq1 = fmaf(w.y, xb.y, aq1); aq1 = fmaf(w.z, xb.z, aq1); aq1 = fmaf(w.w, xb.w, aq1);
        }
        qls[0][ch] = aq0; qls[1][ch] = aq1;
        qT[(b * NQ + n0 + 0) * INNER + ch] = aq0;
        qT[(b * NQ + n0 + 1) * INNER + ch] = aq1;
    }
    __syncthreads();
    {
        int pr = t >> 4, l = t & 15;
        int r = pr >> 3, g = pr & 7;
        float s0 = 0.f, s1 = 0.f;
        #pragma unroll
        for (int e = 0; e < 4; ++e) {
            int jj = l * 4 + e;
            float ev = gelu_exact(fmaf(qls[r][g * 64 + jj], off_w1[jj], off_b1[jj]));
            s0 = fmaf(ev, off_w2[jj], s0);
            s1 = fmaf(ev, off_w2[64 + jj], s1);
        }
        #pragma unroll
        for (int o = 8; o > 0; o >>= 1) {
            s0 += __shfl_xor(s0, o, 64);
            s1 += __shfl_xor(s1, o, 64);
        }
        if (l == 0) {
            float vgx = g01[r][0] + tanhf(s0) * (2.f / 3.f);
            float vgy = g01[r][1] + tanhf(s1) * (2.f / 3.f);
            vg[r][g][0] = vgx; vg[r][g][1] = vgy;
            float* vp = vgrid_g + ((b * GROUPS + g) * NQ + n0 + r) * 2;
            vp[0] = vgx; vp[1] = vgy;
        }
    }
    __syncthreads();
    #pragma unroll
    for (int rep = 0; rep < 2; ++rep) {
        int idx = rep * 256 + t;
        int r = idx >> 8, c = idx & 255, g = c >> 5;
        float x = (vg[r][g][0] + 1.f) * 2.f - 0.5f;
        float y = (vg[r][g][1] + 1.f) * 2.f - 0.5f;
        float x0f = floorf(x), y0f = floorf(y);
        float wx = x - x0f, wy = y - y0f;
        int x0 = (int)x0f, y0 = (int)y0f;
        const float* img = rgb + (b * DIMC + c) * HWT;
        float v00 = samp4(img, y0, x0), v01 = samp4(img, y0, x0 + 1);
        float v10 = samp4(img, y0 + 1, x0), v11 = samp4(img, y0 + 1, x0 + 1);
        kvs[r][c] = v00 * (1.f - wx) * (1.f - wy) + v01 * wx * (1.f - wy)
                  + v10 * (1.f - wx) * wy + v11 * wx * wy;
    }
    __syncthreads();
    #pragma unroll
    for (int rep = 0; rep < 2; ++rep) {
        int ch = rep * 256 + t;
        int g = ch >> 6;
        const float4* kw4 = (const float4*)(k_w + ch * 32);
        const float4* vw4 = (const float4*)(v_w + ch * 32);
        const float4* xa4 = (const float4*)&kvs[0][g * 32];
        const float4* xb4 = (const float4*)&kvs[1][g * 32];
        float ak0 = 0.f, ak1 = 0.f, av0 = 0.f, av1 = 0.f;
        #pragma unroll
        for (int c4 = 0; c4 < 8; ++c4) {
            float4 wk = kw4[c4], wv = vw4[c4];
            float4 xa = xa4[c4], xb = xb4[c4];
            ak0 = fmaf(wk.x, xa.x, ak0); ak0 = fmaf(wk.y, xa.y, ak0); ak0 = fmaf(wk.z, xa.z, ak0); ak0 = fmaf(wk.w, xa.w, ak0);
            ak1 = fmaf(wk.x, xb.x, ak1); ak1 = fmaf(wk.y, xb.y, ak1); ak1 = fmaf(wk.z, xb.z, ak1); ak1 = fmaf(wk.w, xb.w, ak1);
            av0 = fmaf(wv.x, xa.x, av0); av0 = fmaf(wv.y, xa.y, av0); av0 = fmaf(wv.z, xa.z, av0); av0 = fmaf(wv.w, xa.w, av0);
            av1 = fmaf(wv.x, xb.x, av1); av1 = fmaf(wv.y, xb.y, av1); av1 = fmaf(wv.z, xb.z, av1); av1 = fmaf(wv.w, xb.w, av1);
        }
        int hh = ch >> 6, dh = ch & 63;
        float2 kk; kk.x = ak0; kk.y = ak1;
        *(float2*)(kTt + ((b * HEADS + hh) * DH + dh) * NQ + n0) = kk;
        vT[(b * NQ + n0 + 0) * INNER + ch] = av0;
        vT[(b * NQ + n0 + 1) * INNER + ch] = av1;
    }
}

// ---------------- K3b: sim + table-bias + softmax + attn@V ----------------
__global__ __launch_bounds__(256) void k3b_attn(
        const float* __restrict__ qT, const float* __restrict__ kTt,
        const float* __restrict__ vT, const float* __restrict__ tab,
        const float* __restrict__ pose_init, const float* __restrict__ vgrid_g,
        float* __restrict__ aoT) {
    int bg = blockIdx.x >> 5;
    int itile = blockIdx.x & 31;
    int b = bg >> 3, h = bg & 7;
    int i0 = itile * 8;
    int tid = threadIdx.x;

    __shared__ __align__(16) float q_s[8][64];
    __shared__ __align__(16) float attn_s[8][NQ];
    __shared__ __align__(16) float vstage[64][64];
    __shared__ float2 vg_s[NQ];
    __shared__ float2 gi_s[8];
    __shared__ float ssum_s[8];

    for (int idx = tid; idx < 8 * 64; idx += 256) {
        int i = idx >> 6, d = idx & 63;
        q_s[i][d] = qT[(b * NQ + i0 + i) * INNER + h * 64 + d] * 0.125f;
    }
    if (tid < NQ) vg_s[tid] = ((const float2*)vgrid_g)[bg * NQ + tid];
    if (tid >= 240 && tid < 248) {
        int i = tid - 240;
        float2 g;
        g.x = 2.f * pose_init[(b * 2 + 0) * NQ + i0 + i] - 1.f;
        g.y = 2.f * pose_init[(b * 2 + 1) * NQ + i0 + i] - 1.f;
        gi_s[i] = g;
    }
    __syncthreads();

    {
        int jq = tid & 63, ih = tid >> 6;
        float2 gi0 = gi_s[ih], gi1 = gi_s[ih + 4];
        float2 vg0 = vg_s[jq * 4 + 0];
        float2 vg1 = vg_s[jq * 4 + 1];
        float2 vg2 = vg_s[jq * 4 + 2];
        float2 vg3 = vg_s[jq * 4 + 3];
        float b00 = tab_lookup(tab, gi0.x - vg0.x, gi0.y - vg0.y);
        float b01 = tab_lookup(tab, gi0.x - vg1.x, gi0.y - vg1.y);
        float b02 = tab_lookup(tab, gi0.x - vg2.x, gi0.y - vg2.y);
        float b03 = tab_lookup(tab, gi0.x - vg3.x, gi0.y - vg3.y);
        float b10 = tab_lookup(tab, gi1.x - vg0.x, gi1.y - vg0.y);
        float b11 = tab_lookup(tab, gi1.x - vg1.x, gi1.y - vg1.y);
        float b12 = tab_lookup(tab, gi1.x - vg2.x, gi1.y - vg2.y);
        float b13 = tab_lookup(tab, gi1.x - vg3.x, gi1.y - vg3.y);

        const float4* kb4 = (const float4*)(kTt + bg * DH * NQ) + jq;
        float4 s0 = {b00, b01, b02, b03};
        float4 s1 = {b10, b11, b12, b13};
        #pragma unroll 8
        for (int d = 0; d < 64; ++d) {
            float4 kv = kb4[d * 64];
            float q0 = q_s[ih][d], q1 = q_s[ih + 4][d];
            s0.x = fmaf(q0, kv.x, s0.x); s0.y = fmaf(q0, kv.y, s0.y);
            s0.z = fmaf(q0, kv.z, s0.z); s0.w = fmaf(q0, kv.w, s0.w);
            s1.x = fmaf(q1, kv.x, s1.x); s1.y = fmaf(q1, kv.y, s1.y);
            s1.z = fmaf(q1, kv.z, s1.z); s1.w = fmaf(q1, kv.w, s1.w);
        }
        *(float4*)&attn_s[ih][jq * 4] = s0;
        *(float4*)&attn_s[ih + 4][jq * 4] = s1;
    }
    __syncthreads();
    {
        int il = tid >> 5, lane = tid & 31;
        float m = -1e30f;
        for (int jj = 0; jj < 8; ++jj) m = fmaxf(m, attn_s[il][jj * 32 + lane]);
        #pragma unroll
        for (int o = 16; o > 0; o >>= 1) m = fmaxf(m, __shfl_xor(m, o, 32));
        float s = 0.f;
        for (int jj = 0; jj < 8; ++jj) {
            int j = jj * 32 + lane;
            float e = __expf(attn_s[il][j] - m);
            attn_s[il][j] = e;
            s += e;
        }
        #pragma unroll
        for (int o = 16; o > 0; o >>= 1) s += __shfl_xor(s, o, 32);
        if (lane == 0) ssum_s[il] = s;
    }
    // ---- PV over 4 LDS-staged chunks of 64 j ----
    {
        int lane = tid & 31, il = tid >> 5;
        float a0 = 0.f, a1 = 0.f, c0 = 0.f, c1 = 0.f;
        #pragma unroll 1
        for (int jc = 0; jc < 4; ++jc) {
            __syncthreads();
            #pragma unroll
            for (int rep = 0; rep < 4; ++rep) {
                int idx = rep * 256 + tid;
                int row = idx >> 4, c4 = idx & 15;
                float4 v = *(const float4*)(vT + (b * NQ + jc * 64 + row) * INNER + h * 64 + c4 * 4);
                *(float4*)&vstage[row][c4 * 4] = v;
            }
            __syncthreads();
            const float* ar = &attn_s[il][jc * 64];
            #pragma unroll 8
            for (int j = 0; j < 64; j += 2) {
                float w0 = ar[j], w1 = ar[j + 1];
                float2 v0 = *(const float2*)&vstage[j][lane * 2];
                float2 v1 = *(const float2*)&vstage[j + 1][lane * 2];
                a0 = fmaf(w0, v0.x, a0); a1 = fmaf(w0, v0.y, a1);
                c0 = fmaf(w1, v1.x, c0); c1 = fmaf(w1, v1.y, c1);
            }
        }
        float r = 1.f / ssum_s[il];
        float2 res; res.x = (a0 + c0) * r; res.y = (a1 + c1) * r;
        *(float2*)(aoT + (b * NQ + i0 + il) * INNER + h * 64 + lane * 2) = res;
    }
}

// ---------------- K4: final projection 512 -> 256 (row-major out_w) ----------------
__global__ __launch_bounds__(256) void k4_proj(const float* __restrict__ aoT,
        const float* __restrict__ out_w, const float* __restrict__ out_b,
        float* __restrict__ out) {
    int b = blockIdx.x >> 7;
    int n0 = (blockIdx.x & 127) * 2;
    int t = threadIdx.x;
    __shared__ __align__(16) float xl[2][INNER];
    for (int idx = t; idx < 2 * INNER; idx += 256) {
        xl[idx >> 9][idx & 511] = aoT[(b * NQ + n0) * INNER + idx];
    }
    __syncthreads();
    float bo = out_b[t];
    float a0 = bo, a1 = bo;
    const float4* ow4 = (const float4*)(out_w + t * INNER);
    const float4* x04 = (const float4*)&xl[0][0];
    const float4* x14 = (const float4*)&xl[1][0];
    #pragma unroll 4
    for (int c4 = 0; c4 < 128; ++c4) {
        float4 w = ow4[c4];
        float4 x0 = x04[c4], x1 = x14[c4];
        a0 = fmaf(w.x, x0.x, a0); a0 = fmaf(w.y, x0.y, a0); a0 = fmaf(w.z, x0.z, a0); a0 = fmaf(w.w, x0.w, a0);
        a1 = fmaf(w.x, x1.x, a1); a1 = fmaf(w.y, x1.y, a1); a1 = fmaf(w.z, x1.z, a1); a1 = fmaf(w.w, x1.w, a1);
    }
    float2 res; res.x = a0; res.y = a1;
    *(float2*)(out + (b * DIMC + t) * NQ + n0) = res;
}

extern "C" void kernel_launch(void* const* d_in, const int* in_sizes, int n_in,
                              void* d_out, int out_size, void* d_ws, size_t ws_size,
                              hipStream_t stream) {
    const float* pose_feat = (const float*)d_in[0];
    const float* rgb       = (const float*)d_in[1];
    const float* pose_init = (const float*)d_in[2];
    const float* mha_in_w  = (const float*)d_in[3];
    const float* mha_in_b  = (const float*)d_in[4];
    const float* mha_out_w = (const float*)d_in[5];
    const float* mha_out_b = (const float*)d_in[6];
    const float* pe_gauss  = (const float*)d_in[7];
    const float* off_w1    = (const float*)d_in[8];
    const float* off_b1    = (const float*)d_in[9];
    const float* off_w2    = (const float*)d_in[10];
    const float* cpb_w0    = (const float*)d_in[11];
    const float* cpb_b0    = (const float*)d_in[12];
    const float* cpb_w1    = (const float*)d_in[13];
    const float* cpb_b1    = (const float*)d_in[14];
    const float* cpb_w2    = (const float*)d_in[15];
    const float* cpb_b2    = (const float*)d_in[16];
    const float* q_w       = (const float*)d_in[17];
    const float* k_w       = (const float*)d_in[18];
    const float* v_w       = (const float*)d_in[19];
    const float* out_w     = (const float*)d_in[20];
    const float* out_b     = (const float*)d_in[21];

    float* ws    = (float*)d_ws;
    float* kx    = ws;                     // 16384
    float* vx    = kx + 16384;             // 16384
    float* qT    = vx + 16384;             // 524288
    float* kTt   = qT + 524288;            // 524288
    float* vT    = kTt + 524288;           // 524288
    float* vgrid = vT + 524288;            // 16384
    float* aoT   = vgrid + 16384;          // 524288
    float* tab   = aoT + 524288;           // 65536 (256 KB table)
    float* out   = (float*)d_out;

    kprep<<<576, 256, 0, stream>>>(mha_in_w,
        cpb_w0, cpb_b0, cpb_b1, cpb_w1, cpb_w2, cpb_b2, rgb, mha_in_b,
        tab, kx, vx);
    k2_qkv<<<512, 256, 0, stream>>>(pose_feat, rgb, pose_init, mha_in_b,
        mha_in_w, mha_out_w, mha_out_b, pe_gauss, off_w1, off_b1, off_w2,
        q_w, k_w, v_w, kx, vx, qT, kTt, vT, vgrid);
    k3b_attn<<<1024, 256, 0, stream>>>(qT, kTt, vT, tab, pose_init, vgrid, aoT);
    k4_proj<<<512, 256, 0, stream>>>(aoT, out_w, out_b, out);
}

// Round 28
// 112.014 us; speedup vs baseline: 1.3478x; 1.3478x over previous
//
#include <hip/hip_runtime.h>
#include <hip/hip_bf16.h>
#include <math.h>

// DeformableAttention2D — round 28: revert r27's uncoalesced weight reads
// (back to r25's transposed weights, 123.8us) + k2 rebuilt with 512-thread
// blocks: both rows processed concurrently, big GEMVs split across d-halves
// with LDS combine -> 16 waves/CU (was 8). k2 was ~33us latency-bound
// (r27 difference + occupancy 19%).
// Sizes (fixed): B=4, N=256, DIM=256, HEADS=8, GROUPS=8, INNER=512, DH=64.

#define DIMC 256
#define NQ 256
#define HEADS 8
#define GROUPS 8
#define INNER 512
#define DH 64
#define HDX 32
#define HWT 16
#define TS 256
#define UMAXC 1.2995f

typedef unsigned short ushort_t;

__device__ __forceinline__ float gelu_exact(float x) {
    return 0.5f * x * (1.f + erff(x * 0.70710678118654752f));
}
__device__ __forceinline__ float samp4(const float* __restrict__ img, int yi, int xi) {
    bool valid = (xi >= 0) && (xi < 4) && (yi >= 0) && (yi < 4);
    int idx = min(max(yi, 0), 3) * 4 + min(max(xi, 0), 3);
    return valid ? img[idx] : 0.f;
}
__device__ __forceinline__ float tab_lookup(const float* __restrict__ tab,
                                            float px, float py) {
    const float SCL = (float)(TS - 1) / (2.f * UMAXC);
    float u = copysignf(__logf(1.f + fabsf(px)), px);
    float v = copysignf(__logf(1.f + fabsf(py)), py);
    float fx = fminf(fmaxf((u + UMAXC) * SCL, 0.f), (float)(TS - 1) - 1e-3f);
    float fy = fminf(fmaxf((v + UMAXC) * SCL, 0.f), (float)(TS - 1) - 1e-3f);
    int ix = (int)fx, iy = (int)fy;
    float ax = fx - ix, ay = fy - iy;
    const float* r0 = tab + iy * TS + ix;
    float t00 = r0[0], t01 = r0[1], t10 = r0[TS], t11 = r0[TS + 1];
    float t0 = fmaf(ax, t01 - t00, t00);
    float t1 = fmaf(ax, t11 - t10, t10);
    return fmaf(ay, t1 - t0, t0);
}

// ---------------- KPREP: k0 transpose | k3t table | k1 kx/vx ----------------
// blocks 0..1215: weight transposes; 1216..1727: CPB table; 1728..1791: kx/vx
__global__ __launch_bounds__(256) void kprep(
        const float* __restrict__ in_w, const float* __restrict__ mow,
        const float* __restrict__ out_w, const float* __restrict__ q_w,
        const float* __restrict__ k_w, const float* __restrict__ v_w,
        const float* __restrict__ w0, const float* __restrict__ b0,
        const float* __restrict__ b1, const float* __restrict__ w1,
        const float* __restrict__ w2, const float* __restrict__ b2,
        const float* __restrict__ rgb, const float* __restrict__ in_b,
        float* __restrict__ WqT, float* __restrict__ mowT,
        float* __restrict__ owT, float* __restrict__ qwT,
        float* __restrict__ kwT, float* __restrict__ vwT,
        float* __restrict__ tab,
        float* __restrict__ kx, float* __restrict__ vx) {
    __shared__ float w1_s[64][64];
    __shared__ float w0a_s[64], w0b_s[64], b0_s[64];
    __shared__ float2 b1w2_s[64];
    __shared__ __align__(16) float kvin[DIMC];
    int bid = blockIdx.x;
    int tid = threadIdx.x;

    if (bid < 1216) {
        // ---- k0: weight transposes ----
        int idx = bid * 256 + tid;
        if (idx < 65536) {
            int d = idx >> 8, o = idx & 255;
            WqT[idx] = in_w[o * 256 + d];
        } else if (idx < 131072) {
            int k = idx - 65536; int d = k >> 8, o = k & 255;
            mowT[k] = mow[o * 256 + d];
        } else if (idx < 262144) {
            int k = idx - 131072; int c = k >> 8, o = k & 255;
            owT[k] = out_w[o * 512 + c];
        } else if (idx < 278528) {
            int k = idx - 262144; int ci = k >> 9, ch = k & 511;
            qwT[k] = q_w[ch * 32 + ci];
        } else if (idx < 294912) {
            int k = idx - 278528; int ci = k >> 9, ch = k & 511;
            kwT[k] = k_w[ch * 32 + ci];
        } else if (idx < 311296) {
            int k = idx - 294912; int ci = k >> 9, ch = k & 511;
            vwT[k] = v_w[ch * 32 + ci];
        }
    } else if (bid < 1728) {
        // ---- k3t: CPB table build (2 lanes per entry) ----
        for (int r = 0; r < 16; ++r) {
            int idx = r * 256 + tid;
            w1_s[idx >> 6][idx & 63] = w1[idx];
        }
        if (tid < 64) {
            w0a_s[tid] = w0[2 * tid];
            w0b_s[tid] = w0[2 * tid + 1];
            b0_s[tid] = b0[tid];
            float2 bw; bw.x = b1[tid]; bw.y = w2[tid];
            b1w2_s[tid] = bw;
        }
        __syncthreads();

        int gid = (bid - 1216) * 256 + tid;     // 0..131071
        int entry = gid >> 1;
        int half = gid & 1;
        int ty = entry >> 8, tx = entry & (TS - 1);
        const float step = 2.f * UMAXC / (float)(TS - 1);
        float u = fmaf((float)tx, step, -UMAXC);
        float v = fmaf((float)ty, step, -UMAXC);

        float h0[64];
        #pragma unroll
        for (int c = 0; c < 64; ++c)
            h0[c] = fmaxf(fmaf(w0a_s[c], u, fmaf(w0b_s[c], v, b0_s[c])), 0.f);
        float acc = half ? 0.f : b2[0];
        int c2base = half * 32;
        #pragma unroll 1
        for (int c2o = 0; c2o < 32; c2o += 2) {
            int c2 = c2base + c2o;
            float sA0 = 0.f, sA1 = 0.f, sB0 = 0.f, sB1 = 0.f;
            const float* wA = &w1_s[c2][0];
            const float* wB = &w1_s[c2 + 1][0];
            #pragma unroll
            for (int k = 0; k < 64; k += 2) {
                sA0 = fmaf(wA[k], h0[k], sA0);
                sA1 = fmaf(wA[k + 1], h0[k + 1], sA1);
                sB0 = fmaf(wB[k], h0[k], sB0);
                sB1 = fmaf(wB[k + 1], h0[k + 1], sB1);
            }
            float2 bwA = b1w2_s[c2], bwB = b1w2_s[c2 + 1];
            acc += fmaxf(sA0 + sA1 + bwA.x, 0.f) * bwA.y;
            acc += fmaxf(sB0 + sB1 + bwB.x, 0.f) * bwB.y;
        }
        acc += __shfl_xor(acc, 1, 64);
        if (half == 0) tab[ty * TS + tx] = acc;
    } else {
        // ---- k1: kx, vx ----
        int bb = bid - 1728;
        int b = bb >> 4;
        int tt = bb & 15;
        int c = tid;
        float ang = (float)tt * powf(10000.f, -(float)(c >> 1) * (1.f / 128.f));
        float sv = (c & 1) ? cosf(ang) : sinf(ang);
        kvin[c] = rgb[(b * DIMC + c) * HWT + tt] + sv;
        __syncthreads();
        const float4* x4 = (const float4*)kvin;
        const float4* wk4 = (const float4*)(in_w + (DIMC + c) * DIMC);
        const float4* wv4 = (const float4*)(in_w + (2 * DIMC + c) * DIMC);
        float ak0 = in_b[DIMC + c], ak1 = 0.f, av0 = in_b[2 * DIMC + c], av1 = 0.f;
        #pragma unroll 4
        for (int d4 = 0; d4 < 64; ++d4) {
            float4 x = x4[d4], wk = wk4[d4], wv = wv4[d4];
            ak0 = fmaf(wk.x, x.x, ak0); ak1 = fmaf(wk.y, x.y, ak1);
            ak0 = fmaf(wk.z, x.z, ak0); ak1 = fmaf(wk.w, x.w, ak1);
            av0 = fmaf(wv.x, x.x, av0); av1 = fmaf(wv.y, x.y, av1);
            av0 = fmaf(wv.z, x.z, av0); av1 = fmaf(wv.w, x.w, av1);
        }
        kx[(b * HWT + tt) * DIMC + c] = ak0 + ak1;
        vx[(b * HWT + tt) * DIMC + c] = av0 + av1;
    }
}

// ---------------- K2: 512 threads, 2 rows per block (grid 512) ----------------
// r = t>>8, c = t&255 for element-wise phases; GEMVs split d in half/thread.
__global__ __launch_bounds__(512) void k2_qkv(
        const float* __restrict__ pose_feat, const float* __restrict__ rgb,
        const float* __restrict__ pose_init, const float* __restrict__ in_b,
        const float* __restrict__ WqT, const float* __restrict__ mowT,
        const float* __restrict__ mob, const float* __restrict__ pe_gauss,
        const float* __restrict__ off_w1, const float* __restrict__ off_b1,
        const float* __restrict__ off_w2,
        const float* __restrict__ qwT, const float* __restrict__ kwT,
        const float* __restrict__ vwT,
        const float* __restrict__ kx, const float* __restrict__ vx,
        float* __restrict__ qT, float* __restrict__ kTt, float* __restrict__ vT,
        float* __restrict__ vgrid_g) {
    int b = blockIdx.x >> 7;
    int n0 = (blockIdx.x & 127) * 2;
    int t = threadIdx.x;           // 0..511
    int r = t >> 8;                // row (also d-half for GEMV phases)
    int c = t & 255;               // channel
    __shared__ __align__(16) float xs[2][DIMC];
    __shared__ __align__(16) float qxs[2][DIMC];
    __shared__ __align__(16) float ctx[2][DIMC];
    __shared__ __align__(16) float x2[2][DIMC];
    __shared__ float part[2][2][DIMC];   // [d-half][row][c]
    __shared__ float lg[2][128], psm[2][128];
    __shared__ float qls[2][INNER];
    __shared__ float kvs[2][DIMC];
    __shared__ float vg[2][GROUPS][2];
    __shared__ float g01[2][2];

    if (t < 4) {
        int rr = t >> 1, comp = t & 1;
        g01[rr][comp] = 2.f * pose_init[(b * 2 + comp) * NQ + n0 + rr] - 1.f;
    }
    float pf = pose_feat[(b * DIMC + c) * NQ + n0 + r];
    __syncthreads();
    {
        // xs[r][c] = pose_feat + random-fourier point emb
        int j = c & 127;
        float pj0 = pe_gauss[j], pj1 = pe_gauss[128 + j];
        float cc = (g01[r][0] * pj0 + g01[r][1] * pj1) * 6.28318530717958648f;
        float sc = (c < 128) ? sinf(cc) : cosf(cc);
        xs[r][c] = pf + sc;
    }
    __syncthreads();
    {
        // Wq GEMV, split across d-halves (h = r index reused)
        int h = r;
        float bq = (h == 0) ? in_b[c] : 0.f;
        float a0 = bq, a1 = bq;
        int dbase = h * 128;
        #pragma unroll 4
        for (int d4 = 0; d4 < 32; ++d4) {
            int d = dbase + d4 * 4;
            float w0 = WqT[(d + 0) * DIMC + c];
            float w1 = WqT[(d + 1) * DIMC + c];
            float w2 = WqT[(d + 2) * DIMC + c];
            float w3 = WqT[(d + 3) * DIMC + c];
            float4 x0 = *(const float4*)&xs[0][d];
            float4 x1 = *(const float4*)&xs[1][d];
            a0 = fmaf(w0, x0.x, a0); a0 = fmaf(w1, x0.y, a0); a0 = fmaf(w2, x0.z, a0); a0 = fmaf(w3, x0.w, a0);
            a1 = fmaf(w0, x1.x, a1); a1 = fmaf(w1, x1.y, a1); a1 = fmaf(w2, x1.z, a1); a1 = fmaf(w3, x1.w, a1);
        }
        part[h][0][c] = a0; part[h][1][c] = a1;
    }
    __syncthreads();
    qxs[r][c] = part[0][r][c] + part[1][r][c];
    __syncthreads();
    {
        // cross-attn logits: 2r x 8hh x 16tt x 2half
        int half = t & 1, tt = (t >> 1) & 15, hh = (t >> 5) & 7, rr = t >> 8;
        const float4* kp = (const float4*)(kx + (b * HWT + tt) * DIMC + hh * HDX) + half * 4;
        const float4* qp = (const float4*)(&qxs[rr][hh * HDX]) + half * 4;
        float a = 0.f;
        #pragma unroll
        for (int d4 = 0; d4 < 4; ++d4) {
            float4 k4 = kp[d4], q4 = qp[d4];
            a = fmaf(q4.x, k4.x, a); a = fmaf(q4.y, k4.y, a);
            a = fmaf(q4.z, k4.z, a); a = fmaf(q4.w, k4.w, a);
        }
        a += __shfl_xor(a, 1, 64);
        if (half == 0) lg[rr][hh * 16 + tt] = a * 0.17677669529663689f;
    }
    __syncthreads();
    if (t < 16) {
        int rr = t >> 3, hh = t & 7;
        float m = -1e30f;
        for (int tt = 0; tt < 16; ++tt) m = fmaxf(m, lg[rr][hh * 16 + tt]);
        float s = 0.f;
        for (int tt = 0; tt < 16; ++tt) {
            float e = __expf(lg[rr][hh * 16 + tt] - m);
            psm[rr][hh * 16 + tt] = e; s += e;
        }
        float rs = 1.f / s;
        for (int tt = 0; tt < 16; ++tt) psm[rr][hh * 16 + tt] *= rs;
    }
    __syncthreads();
    {
        // ctx[r][c] = attn @ vx
        int hh = c >> 5;
        const float* vp = vx + b * HWT * DIMC + c;
        float a = 0.f;
        #pragma unroll
        for (int tt = 0; tt < 16; ++tt)
            a = fmaf(psm[r][hh * 16 + tt], vp[tt * DIMC], a);
        ctx[r][c] = a;
    }
    __syncthreads();
    {
        // mow GEMV, split across d-halves
        int h = r;
        float bm = (h == 0) ? mob[c] : 0.f;
        float a0 = bm, a1 = bm;
        int dbase = h * 128;
        #pragma unroll 4
        for (int d4 = 0; d4 < 32; ++d4) {
            int d = dbase + d4 * 4;
            float w0 = mowT[(d + 0) * DIMC + c];
            float w1 = mowT[(d + 1) * DIMC + c];
            float w2 = mowT[(d + 2) * DIMC + c];
            float w3 = mowT[(d + 3) * DIMC + c];
            float4 c0 = *(const float4*)&ctx[0][d];
            float4 c1 = *(const float4*)&ctx[1][d];
            a0 = fmaf(w0, c0.x, a0); a0 = fmaf(w1, c0.y, a0); a0 = fmaf(w2, c0.z, a0); a0 = fmaf(w3, c0.w, a0);
            a1 = fmaf(w0, c1.x, a1); a1 = fmaf(w1, c1.y, a1); a1 = fmaf(w2, c1.z, a1); a1 = fmaf(w3, c1.w, a1);
        }
        part[h][0][c] = a0; part[h][1][c] = a1;
    }
    __syncthreads();
    x2[r][c] = pf + part[0][r][c] + part[1][r][c];
    __syncthreads();
    {
        // grouped q projection: ch = t, both rows
        int ch = t;
        int g = ch >> 6;
        float aq0 = 0.f, aq1 = 0.f;
        #pragma unroll
        for (int ci = 0; ci < 32; ++ci) {
            float w = qwT[ci * INNER + ch];
            aq0 = fmaf(w, x2[0][g * 32 + ci], aq0);
            aq1 = fmaf(w, x2[1][g * 32 + ci], aq1);
        }
        qls[0][ch] = aq0; qls[1][ch] = aq1;
        qT[(b * NQ + n0 + 0) * INNER + ch] = aq0;
        qT[(b * NQ + n0 + 1) * INNER + ch] = aq1;
    }
    __syncthreads();
    if (t < 256) {
        int pr = t >> 4, l = t & 15;
        int rr = pr >> 3, g = pr & 7;
        float s0 = 0.f, s1 = 0.f;
        #pragma unroll
        for (int e = 0; e < 4; ++e) {
            int jj = l * 4 + e;
            float ev = gelu_exact(fmaf(qls[rr][g * 64 + jj], off_w1[jj], off_b1[jj]));
            s0 = fmaf(ev, off_w2[jj], s0);
            s1 = fmaf(ev, off_w2[64 + jj], s1);
        }
        #pragma unroll
        for (int o = 8; o > 0; o >>= 1) {
            s0 += __shfl_xor(s0, o, 64);
            s1 += __shfl_xor(s1, o, 64);
        }
        if (l == 0) {
            float vgx = g01[rr][0] + tanhf(s0) * (2.f / 3.f);
            float vgy = g01[rr][1] + tanhf(s1) * (2.f / 3.f);
            vg[rr][g][0] = vgx; vg[rr][g][1] = vgy;
            float* vp = vgrid_g + ((b * GROUPS + g) * NQ + n0 + rr) * 2;
            vp[0] = vgx; vp[1] = vgy;
        }
    }
    __syncthreads();
    {
        // bilinear sampling: 512 entries, one per thread
        int g = c >> 5;
        float x = (vg[r][g][0] + 1.f) * 2.f - 0.5f;
        float y = (vg[r][g][1] + 1.f) * 2.f - 0.5f;
        float x0f = floorf(x), y0f = floorf(y);
        float wx = x - x0f, wy = y - y0f;
        int x0 = (int)x0f, y0 = (int)y0f;
        const float* img = rgb + (b * DIMC + c) * HWT;
        float v00 = samp4(img, y0, x0), v01 = samp4(img, y0, x0 + 1);
        float v10 = samp4(img, y0 + 1, x0), v11 = samp4(img, y0 + 1, x0 + 1);
        kvs[r][c] = v00 * (1.f - wx) * (1.f - wy) + v01 * wx * (1.f - wy)
                  + v10 * (1.f - wx) * wy + v11 * wx * wy;
    }
    __syncthreads();
    {
        // grouped k/v projection: ch = t, both rows
        int ch = t;
        int g = ch >> 6;
        float ak0 = 0.f, ak1 = 0.f, av0 = 0.f, av1 = 0.f;
        #pragma unroll
        for (int ci = 0; ci < 32; ++ci) {
            float wk = kwT[ci * INNER + ch];
            float wv = vwT[ci * INNER + ch];
            float x0 = kvs[0][g * 32 + ci];
            float x1 = kvs[1][g * 32 + ci];
            ak0 = fmaf(wk, x0, ak0); ak1 = fmaf(wk, x1, ak1);
            av0 = fmaf(wv, x0, av0); av1 = fmaf(wv, x1, av1);
        }
        int hh = ch >> 6, dh = ch & 63;
        float2 kk; kk.x = ak0; kk.y = ak1;
        *(float2*)(kTt + ((b * HEADS + hh) * DH + dh) * NQ + n0) = kk;
        vT[(b * NQ + n0 + 0) * INNER + ch] = av0;
        vT[(b * NQ + n0 + 1) * INNER + ch] = av1;
    }
}

// ---------------- K3b: sim + table-bias + softmax + attn@V ----------------
__global__ __launch_bounds__(256) void k3b_attn(
        const float* __restrict__ qT, const float* __restrict__ kTt,
        const float* __restrict__ vT, const float* __restrict__ tab,
        const float* __restrict__ pose_init, const float* __restrict__ vgrid_g,
        float* __restrict__ aoT) {
    int bg = blockIdx.x >> 5;
    int itile = blockIdx.x & 31;
    int b = bg >> 3, h = bg & 7;
    int i0 = itile * 8;
    int tid = threadIdx.x;

    __shared__ __align__(16) float q_s[8][64];
    __shared__ __align__(16) float attn_s[8][NQ];
    __shared__ __align__(16) float vstage[64][64];
    __shared__ float2 vg_s[NQ];
    __shared__ float2 gi_s[8];
    __shared__ float ssum_s[8];

    for (int idx = tid; idx < 8 * 64; idx += 256) {
        int i = idx >> 6, d = idx & 63;
        q_s[i][d] = qT[(b * NQ + i0 + i) * INNER + h * 64 + d] * 0.125f;
    }
    if (tid < NQ) vg_s[tid] = ((const float2*)vgrid_g)[bg * NQ + tid];
    if (tid >= 240 && tid < 248) {
        int i = tid - 240;
        float2 g;
        g.x = 2.f * pose_init[(b * 2 + 0) * NQ + i0 + i] - 1.f;
        g.y = 2.f * pose_init[(b * 2 + 1) * NQ + i0 + i] - 1.f;
        gi_s[i] = g;
    }
    __syncthreads();

    {
        int jq = tid & 63, ih = tid >> 6;
        float2 gi0 = gi_s[ih], gi1 = gi_s[ih + 4];
        float2 vg0 = vg_s[jq * 4 + 0];
        float2 vg1 = vg_s[jq * 4 + 1];
        float2 vg2 = vg_s[jq * 4 + 2];
        float2 vg3 = vg_s[jq * 4 + 3];
        float b00 = tab_lookup(tab, gi0.x - vg0.x, gi0.y - vg0.y);
        float b01 = tab_lookup(tab, gi0.x - vg1.x, gi0.y - vg1.y);
        float b02 = tab_lookup(tab, gi0.x - vg2.x, gi0.y - vg2.y);
        float b03 = tab_lookup(tab, gi0.x - vg3.x, gi0.y - vg3.y);
        float b10 = tab_lookup(tab, gi1.x - vg0.x, gi1.y - vg0.y);
        float b11 = tab_lookup(tab, gi1.x - vg1.x, gi1.y - vg1.y);
        float b12 = tab_lookup(tab, gi1.x - vg2.x, gi1.y - vg2.y);
        float b13 = tab_lookup(tab, gi1.x - vg3.x, gi1.y - vg3.y);

        const float4* kb4 = (const float4*)(kTt + bg * DH * NQ) + jq;
        float4 s0 = {b00, b01, b02, b03};
        float4 s1 = {b10, b11, b12, b13};
        #pragma unroll 8
        for (int d = 0; d < 64; ++d) {
            float4 kv = kb4[d * 64];
            float q0 = q_s[ih][d], q1 = q_s[ih + 4][d];
            s0.x = fmaf(q0, kv.x, s0.x); s0.y = fmaf(q0, kv.y, s0.y);
            s0.z = fmaf(q0, kv.z, s0.z); s0.w = fmaf(q0, kv.w, s0.w);
            s1.x = fmaf(q1, kv.x, s1.x); s1.y = fmaf(q1, kv.y, s1.y);
            s1.z = fmaf(q1, kv.z, s1.z); s1.w = fmaf(q1, kv.w, s1.w);
        }
        *(float4*)&attn_s[ih][jq * 4] = s0;
        *(float4*)&attn_s[ih + 4][jq * 4] = s1;
    }
    __syncthreads();
    {
        int il = tid >> 5, lane = tid & 31;
        float m = -1e30f;
        for (int jj = 0; jj < 8; ++jj) m = fmaxf(m, attn_s[il][jj * 32 + lane]);
        #pragma unroll
        for (int o = 16; o > 0; o >>= 1) m = fmaxf(m, __shfl_xor(m, o, 32));
        float s = 0.f;
        for (int jj = 0; jj < 8; ++jj) {
            int j = jj * 32 + lane;
            float e = __expf(attn_s[il][j] - m);
            attn_s[il][j] = e;
            s += e;
        }
        #pragma unroll
        for (int o = 16; o > 0; o >>= 1) s += __shfl_xor(s, o, 32);
        if (lane == 0) ssum_s[il] = s;
    }
    // ---- PV over 4 LDS-staged chunks of 64 j ----
    {
        int lane = tid & 31, il = tid >> 5;
        float a0 = 0.f, a1 = 0.f, c0 = 0.f, c1 = 0.f;
        #pragma unroll 1
        for (int jc = 0; jc < 4; ++jc) {
            __syncthreads();
            #pragma unroll
            for (int rep = 0; rep < 4; ++rep) {
                int idx = rep * 256 + tid;
                int row = idx >> 4, c4 = idx & 15;
                float4 v = *(const float4*)(vT + (b * NQ + jc * 64 + row) * INNER + h * 64 + c4 * 4);
                *(float4*)&vstage[row][c4 * 4] = v;
            }
            __syncthreads();
            const float* ar = &attn_s[il][jc * 64];
            #pragma unroll 8
            for (int j = 0; j < 64; j += 2) {
                float w0 = ar[j], w1 = ar[j + 1];
                float2 v0 = *(const float2*)&vstage[j][lane * 2];
                float2 v1 = *(const float2*)&vstage[j + 1][lane * 2];
                a0 = fmaf(w0, v0.x, a0); a1 = fmaf(w0, v0.y, a1);
                c0 = fmaf(w1, v1.x, c0); c1 = fmaf(w1, v1.y, c1);
            }
        }
        float r = 1.f / ssum_s[il];
        float2 res; res.x = (a0 + c0) * r; res.y = (a1 + c1) * r;
        *(float2*)(aoT + (b * NQ + i0 + il) * INNER + h * 64 + lane * 2) = res;
    }
}

// ---------------- K4: final projection 512 -> 256 (coalesced owT) ----------------
__global__ __launch_bounds__(256) void k4_proj(const float* __restrict__ aoT,
        const float* __restrict__ owT, const float* __restrict__ out_b,
        float* __restrict__ out) {
    int b = blockIdx.x >> 6;
    int n0 = (blockIdx.x & 63) * 4;
    int t = threadIdx.x;
    __shared__ __align__(16) float xl[4][INNER];
    for (int idx = t; idx < 4 * INNER; idx += 256) {
        xl[idx >> 9][idx & 511] = aoT[(b * NQ + n0) * INNER + idx];
    }
    __syncthreads();
    float bo = out_b[t];
    float a0 = bo, a1 = bo, a2 = bo, a3 = bo;
    #pragma unroll 2
    for (int c4 = 0; c4 < 128; ++c4) {
        int c = c4 * 4;
        float w0 = owT[(c + 0) * DIMC + t];
        float w1 = owT[(c + 1) * DIMC + t];
        float w2 = owT[(c + 2) * DIMC + t];
        float w3 = owT[(c + 3) * DIMC + t];
        float4 x0 = *(const float4*)&xl[0][c];
        float4 x1 = *(const float4*)&xl[1][c];
        float4 x2 = *(const float4*)&xl[2][c];
        float4 x3 = *(const float4*)&xl[3][c];
        a0 = fmaf(w0, x0.x, a0); a0 = fmaf(w1, x0.y, a0); a0 = fmaf(w2, x0.z, a0); a0 = fmaf(w3, x0.w, a0);
        a1 = fmaf(w0, x1.x, a1); a1 = fmaf(w1, x1.y, a1); a1 = fmaf(w2, x1.z, a1); a1 = fmaf(w3, x1.w, a1);
        a2 = fmaf(w0, x2.x, a2); a2 = fmaf(w1, x2.y, a2); a2 = fmaf(w2, x2.z, a2); a2 = fmaf(w3, x2.w, a2);
        a3 = fmaf(w0, x3.x, a3); a3 = fmaf(w1, x3.y, a3); a3 = fmaf(w2, x3.z, a3); a3 = fmaf(w3, x3.w, a3);
    }
    float4 res; res.x = a0; res.y = a1; res.z = a2; res.w = a3;
    *(float4*)(out + (b * DIMC + t) * NQ + n0) = res;
}

extern "C" void kernel_launch(void* const* d_in, const int* in_sizes, int n_in,
                              void* d_out, int out_size, void* d_ws, size_t ws_size,
                              hipStream_t stream) {
    const float* pose_feat = (const float*)d_in[0];
    const float* rgb       = (const float*)d_in[1];
    const float* pose_init = (const float*)d_in[2];
    const float* mha_in_w  = (const float*)d_in[3];
    const float* mha_in_b  = (const float*)d_in[4];
    const float* mha_out_w = (const float*)d_in[5];
    const float* mha_out_b = (const float*)d_in[6];
    const float* pe_gauss  = (const float*)d_in[7];
    const float* off_w1    = (const float*)d_in[8];
    const float* off_b1    = (const float*)d_in[9];
    const float* off_w2    = (const float*)d_in[10];
    const float* cpb_w0    = (const float*)d_in[11];
    const float* cpb_b0    = (const float*)d_in[12];
    const float* cpb_w1    = (const float*)d_in[13];
    const float* cpb_b1    = (const float*)d_in[14];
    const float* cpb_w2    = (const float*)d_in[15];
    const float* cpb_b2    = (const float*)d_in[16];
    const float* q_w       = (const float*)d_in[17];
    const float* k_w       = (const float*)d_in[18];
    const float* v_w       = (const float*)d_in[19];
    const float* out_w     = (const float*)d_in[20];
    const float* out_b     = (const float*)d_in[21];

    float* ws    = (float*)d_ws;
    float* kx    = ws;                     // 16384
    float* vx    = kx + 16384;             // 16384
    float* qT    = vx + 16384;             // 524288
    float* kTt   = qT + 524288;            // 524288
    float* vT    = kTt + 524288;           // 524288
    float* vgrid = vT + 524288;            // 16384
    float* aoT   = vgrid + 16384;          // 524288
    float* WqT   = aoT + 524288;           // 65536
    float* mowT  = WqT + 65536;            // 65536
    float* owT   = mowT + 65536;           // 131072
    float* qwT   = owT + 131072;           // 16384
    float* kwT   = qwT + 16384;            // 16384
    float* vwT   = kwT + 16384;            // 16384
    float* tab   = vwT + 16384;            // 65536 (256 KB table)
    float* out   = (float*)d_out;

    kprep<<<1792, 256, 0, stream>>>(mha_in_w, mha_out_w, out_w, q_w, k_w, v_w,
        cpb_w0, cpb_b0, cpb_b1, cpb_w1, cpb_w2, cpb_b2, rgb, mha_in_b,
        WqT, mowT, owT, qwT, kwT, vwT, tab, kx, vx);
    k2_qkv<<<512, 512, 0, stream>>>(pose_feat, rgb, pose_init, mha_in_b,
        WqT, mowT, mha_out_b, pe_gauss, off_w1, off_b1, off_w2, qwT, kwT, vwT,
        kx, vx, qT, kTt, vT, vgrid);
    k3b_attn<<<1024, 256, 0, stream>>>(qT, kTt, vT, tab, pose_init, vgrid, aoT);
    k4_proj<<<256, 256, 0, stream>>>(aoT, owT, out_b, out);
}

// Round 29
// 110.059 us; speedup vs baseline: 1.3718x; 1.0178x over previous
//
#include <hip/hip_runtime.h>
#include <hip/hip_bf16.h>
#include <math.h>

// DeformableAttention2D — round 29: round-28 (112.0us) + LDS-tiled coalesced
// weight transposes. k0's 1216 scalar stride-1KB blocks -> 88 float4-coalesced
// 64x64-tile blocks (read rows, barrier, write cols via padded tile[64][65]).
// kprep grid 1792 -> 664. k2/k3b/k4 identical to round 28.
// Sizes (fixed): B=4, N=256, DIM=256, HEADS=8, GROUPS=8, INNER=512, DH=64.

#define DIMC 256
#define NQ 256
#define HEADS 8
#define GROUPS 8
#define INNER 512
#define DH 64
#define HDX 32
#define HWT 16
#define TS 256
#define UMAXC 1.2995f

typedef unsigned short ushort_t;

__device__ __forceinline__ float gelu_exact(float x) {
    return 0.5f * x * (1.f + erff(x * 0.70710678118654752f));
}
__device__ __forceinline__ float samp4(const float* __restrict__ img, int yi, int xi) {
    bool valid = (xi >= 0) && (xi < 4) && (yi >= 0) && (yi < 4);
    int idx = min(max(yi, 0), 3) * 4 + min(max(xi, 0), 3);
    return valid ? img[idx] : 0.f;
}
__device__ __forceinline__ float tab_lookup(const float* __restrict__ tab,
                                            float px, float py) {
    const float SCL = (float)(TS - 1) / (2.f * UMAXC);
    float u = copysignf(__logf(1.f + fabsf(px)), px);
    float v = copysignf(__logf(1.f + fabsf(py)), py);
    float fx = fminf(fmaxf((u + UMAXC) * SCL, 0.f), (float)(TS - 1) - 1e-3f);
    float fy = fminf(fmaxf((v + UMAXC) * SCL, 0.f), (float)(TS - 1) - 1e-3f);
    int ix = (int)fx, iy = (int)fy;
    float ax = fx - ix, ay = fy - iy;
    const float* r0 = tab + iy * TS + ix;
    float t00 = r0[0], t01 = r0[1], t10 = r0[TS], t11 = r0[TS + 1];
    float t0 = fmaf(ax, t01 - t00, t00);
    float t1 = fmaf(ax, t11 - t10, t10);
    return fmaf(ay, t1 - t0, t0);
}

// ---------------- KPREP ----------------
// bid 0..15  : WqT   (in_w[:256] 256x256 -> T)
// bid 16..31 : mowT  (mow 256x256 -> T)
// bid 32..63 : owT   (out_w 256x512 -> 512x256)
// bid 64..87 : qwT/kwT/vwT (512x32 -> 32x512, 8 tiles each)
// bid 88..599: CPB table (512 blocks)
// bid 600..663: kx/vx (64 blocks)
__global__ __launch_bounds__(256) void kprep(
        const float* __restrict__ in_w, const float* __restrict__ mow,
        const float* __restrict__ out_w, const float* __restrict__ q_w,
        const float* __restrict__ k_w, const float* __restrict__ v_w,
        const float* __restrict__ w0, const float* __restrict__ b0,
        const float* __restrict__ b1, const float* __restrict__ w1,
        const float* __restrict__ w2, const float* __restrict__ b2,
        const float* __restrict__ rgb, const float* __restrict__ in_b,
        float* __restrict__ WqT, float* __restrict__ mowT,
        float* __restrict__ owT, float* __restrict__ qwT,
        float* __restrict__ kwT, float* __restrict__ vwT,
        float* __restrict__ tab,
        float* __restrict__ kx, float* __restrict__ vx) {
    __shared__ float tile[64][65];
    __shared__ float w1_s[64][64];
    __shared__ float w0a_s[64], w0b_s[64], b0_s[64];
    __shared__ float2 b1w2_s[64];
    __shared__ __align__(16) float kvin[DIMC];
    int bid = blockIdx.x;
    int tid = threadIdx.x;

    if (bid < 32) {
        // ---- 256x256 transpose, 64x64 tiles ----
        const float* src = (bid < 16) ? in_w : mow;
        float* dst = (bid < 16) ? WqT : mowT;
        int tno = bid & 15;
        int r0 = (tno >> 2) * 64, c0 = (tno & 3) * 64;
        #pragma unroll
        for (int p = 0; p < 4; ++p) {
            int row = (tid >> 4) + p * 16;
            int c4 = (tid & 15) * 4;
            float4 v = *(const float4*)(src + (r0 + row) * 256 + c0 + c4);
            tile[row][c4] = v.x; tile[row][c4 + 1] = v.y;
            tile[row][c4 + 2] = v.z; tile[row][c4 + 3] = v.w;
        }
        __syncthreads();
        #pragma unroll
        for (int p = 0; p < 4; ++p) {
            int row = (tid >> 4) + p * 16;
            int c4 = (tid & 15) * 4;
            float4 w;
            w.x = tile[c4][row]; w.y = tile[c4 + 1][row];
            w.z = tile[c4 + 2][row]; w.w = tile[c4 + 3][row];
            *(float4*)(dst + (c0 + row) * 256 + r0 + c4) = w;
        }
    } else if (bid < 64) {
        // ---- out_w 256x512 -> owT 512x256 ----
        int tno = bid - 32;
        int r0 = (tno >> 3) * 64, c0 = (tno & 7) * 64;
        #pragma unroll
        for (int p = 0; p < 4; ++p) {
            int row = (tid >> 4) + p * 16;
            int c4 = (tid & 15) * 4;
            float4 v = *(const float4*)(out_w + (r0 + row) * 512 + c0 + c4);
            tile[row][c4] = v.x; tile[row][c4 + 1] = v.y;
            tile[row][c4 + 2] = v.z; tile[row][c4 + 3] = v.w;
        }
        __syncthreads();
        #pragma unroll
        for (int p = 0; p < 4; ++p) {
            int row = (tid >> 4) + p * 16;
            int c4 = (tid & 15) * 4;
            float4 w;
            w.x = tile[c4][row]; w.y = tile[c4 + 1][row];
            w.z = tile[c4 + 2][row]; w.w = tile[c4 + 3][row];
            *(float4*)(owT + (c0 + row) * 256 + r0 + c4) = w;
        }
    } else if (bid < 88) {
        // ---- q_w/k_w/v_w 512x32 -> 32x512, 64-ch tiles ----
        const float* src = (bid < 72) ? q_w : (bid < 80) ? k_w : v_w;
        float* dst = (bid < 72) ? qwT : (bid < 80) ? kwT : vwT;
        int ch0 = ((bid - 64) & 7) * 64;
        #pragma unroll
        for (int p = 0; p < 2; ++p) {
            int row = (tid >> 3) + p * 32;
            int c4 = (tid & 7) * 4;
            float4 v = *(const float4*)(src + (ch0 + row) * 32 + c4);
            tile[row][c4] = v.x; tile[row][c4 + 1] = v.y;
            tile[row][c4 + 2] = v.z; tile[row][c4 + 3] = v.w;
        }
        __syncthreads();
        #pragma unroll
        for (int p = 0; p < 2; ++p) {
            int ci = (tid >> 4) + p * 16;
            int ch4 = (tid & 15) * 4;
            float4 w;
            w.x = tile[ch4][ci]; w.y = tile[ch4 + 1][ci];
            w.z = tile[ch4 + 2][ci]; w.w = tile[ch4 + 3][ci];
            *(float4*)(dst + ci * INNER + ch0 + ch4) = w;
        }
    } else if (bid < 600) {
        // ---- k3t: CPB table build (2 lanes per entry) ----
        for (int r = 0; r < 16; ++r) {
            int idx = r * 256 + tid;
            w1_s[idx >> 6][idx & 63] = w1[idx];
        }
        if (tid < 64) {
            w0a_s[tid] = w0[2 * tid];
            w0b_s[tid] = w0[2 * tid + 1];
            b0_s[tid] = b0[tid];
            float2 bw; bw.x = b1[tid]; bw.y = w2[tid];
            b1w2_s[tid] = bw;
        }
        __syncthreads();

        int gid = (bid - 88) * 256 + tid;       // 0..131071
        int entry = gid >> 1;
        int half = gid & 1;
        int ty = entry >> 8, tx = entry & (TS - 1);
        const float step = 2.f * UMAXC / (float)(TS - 1);
        float u = fmaf((float)tx, step, -UMAXC);
        float v = fmaf((float)ty, step, -UMAXC);

        float h0[64];
        #pragma unroll
        for (int c = 0; c < 64; ++c)
            h0[c] = fmaxf(fmaf(w0a_s[c], u, fmaf(w0b_s[c], v, b0_s[c])), 0.f);
        float acc = half ? 0.f : b2[0];
        int c2base = half * 32;
        #pragma unroll 1
        for (int c2o = 0; c2o < 32; c2o += 2) {
            int c2 = c2base + c2o;
            float sA0 = 0.f, sA1 = 0.f, sB0 = 0.f, sB1 = 0.f;
            const float* wA = &w1_s[c2][0];
            const float* wB = &w1_s[c2 + 1][0];
            #pragma unroll
            for (int k = 0; k < 64; k += 2) {
                sA0 = fmaf(wA[k], h0[k], sA0);
                sA1 = fmaf(wA[k + 1], h0[k + 1], sA1);
                sB0 = fmaf(wB[k], h0[k], sB0);
                sB1 = fmaf(wB[k + 1], h0[k + 1], sB1);
            }
            float2 bwA = b1w2_s[c2], bwB = b1w2_s[c2 + 1];
            acc += fmaxf(sA0 + sA1 + bwA.x, 0.f) * bwA.y;
            acc += fmaxf(sB0 + sB1 + bwB.x, 0.f) * bwB.y;
        }
        acc += __shfl_xor(acc, 1, 64);
        if (half == 0) tab[ty * TS + tx] = acc;
    } else {
        // ---- k1: kx, vx ----
        int bb = bid - 600;
        int b = bb >> 4;
        int tt = bb & 15;
        int c = tid;
        float ang = (float)tt * powf(10000.f, -(float)(c >> 1) * (1.f / 128.f));
        float sv = (c & 1) ? cosf(ang) : sinf(ang);
        kvin[c] = rgb[(b * DIMC + c) * HWT + tt] + sv;
        __syncthreads();
        const float4* x4 = (const float4*)kvin;
        const float4* wk4 = (const float4*)(in_w + (DIMC + c) * DIMC);
        const float4* wv4 = (const float4*)(in_w + (2 * DIMC + c) * DIMC);
        float ak0 = in_b[DIMC + c], ak1 = 0.f, av0 = in_b[2 * DIMC + c], av1 = 0.f;
        #pragma unroll 4
        for (int d4 = 0; d4 < 64; ++d4) {
            float4 x = x4[d4], wk = wk4[d4], wv = wv4[d4];
            ak0 = fmaf(wk.x, x.x, ak0); ak1 = fmaf(wk.y, x.y, ak1);
            ak0 = fmaf(wk.z, x.z, ak0); ak1 = fmaf(wk.w, x.w, ak1);
            av0 = fmaf(wv.x, x.x, av0); av1 = fmaf(wv.y, x.y, av1);
            av0 = fmaf(wv.z, x.z, av0); av1 = fmaf(wv.w, x.w, av1);
        }
        kx[(b * HWT + tt) * DIMC + c] = ak0 + ak1;
        vx[(b * HWT + tt) * DIMC + c] = av0 + av1;
    }
}

// ---------------- K2: 512 threads, 2 rows per block (grid 512) ----------------
__global__ __launch_bounds__(512) void k2_qkv(
        const float* __restrict__ pose_feat, const float* __restrict__ rgb,
        const float* __restrict__ pose_init, const float* __restrict__ in_b,
        const float* __restrict__ WqT, const float* __restrict__ mowT,
        const float* __restrict__ mob, const float* __restrict__ pe_gauss,
        const float* __restrict__ off_w1, const float* __restrict__ off_b1,
        const float* __restrict__ off_w2,
        const float* __restrict__ qwT, const float* __restrict__ kwT,
        const float* __restrict__ vwT,
        const float* __restrict__ kx, const float* __restrict__ vx,
        float* __restrict__ qT, float* __restrict__ kTt, float* __restrict__ vT,
        float* __restrict__ vgrid_g) {
    int b = blockIdx.x >> 7;
    int n0 = (blockIdx.x & 127) * 2;
    int t = threadIdx.x;           // 0..511
    int r = t >> 8;                // row (also d-half for GEMV phases)
    int c = t & 255;               // channel
    __shared__ __align__(16) float xs[2][DIMC];
    __shared__ __align__(16) float qxs[2][DIMC];
    __shared__ __align__(16) float ctx[2][DIMC];
    __shared__ __align__(16) float x2[2][DIMC];
    __shared__ float part[2][2][DIMC];   // [d-half][row][c]
    __shared__ float lg[2][128], psm[2][128];
    __shared__ float qls[2][INNER];
    __shared__ float kvs[2][DIMC];
    __shared__ float vg[2][GROUPS][2];
    __shared__ float g01[2][2];

    if (t < 4) {
        int rr = t >> 1, comp = t & 1;
        g01[rr][comp] = 2.f * pose_init[(b * 2 + comp) * NQ + n0 + rr] - 1.f;
    }
    float pf = pose_feat[(b * DIMC + c) * NQ + n0 + r];
    __syncthreads();
    {
        int j = c & 127;
        float pj0 = pe_gauss[j], pj1 = pe_gauss[128 + j];
        float cc = (g01[r][0] * pj0 + g01[r][1] * pj1) * 6.28318530717958648f;
        float sc = (c < 128) ? sinf(cc) : cosf(cc);
        xs[r][c] = pf + sc;
    }
    __syncthreads();
    {
        int h = r;
        float bq = (h == 0) ? in_b[c] : 0.f;
        float a0 = bq, a1 = bq;
        int dbase = h * 128;
        #pragma unroll 4
        for (int d4 = 0; d4 < 32; ++d4) {
            int d = dbase + d4 * 4;
            float w0 = WqT[(d + 0) * DIMC + c];
            float w1 = WqT[(d + 1) * DIMC + c];
            float w2 = WqT[(d + 2) * DIMC + c];
            float w3 = WqT[(d + 3) * DIMC + c];
            float4 x0 = *(const float4*)&xs[0][d];
            float4 x1 = *(const float4*)&xs[1][d];
            a0 = fmaf(w0, x0.x, a0); a0 = fmaf(w1, x0.y, a0); a0 = fmaf(w2, x0.z, a0); a0 = fmaf(w3, x0.w, a0);
            a1 = fmaf(w0, x1.x, a1); a1 = fmaf(w1, x1.y, a1); a1 = fmaf(w2, x1.z, a1); a1 = fmaf(w3, x1.w, a1);
        }
        part[h][0][c] = a0; part[h][1][c] = a1;
    }
    __syncthreads();
    qxs[r][c] = part[0][r][c] + part[1][r][c];
    __syncthreads();
    {
        int half = t & 1, tt = (t >> 1) & 15, hh = (t >> 5) & 7, rr = t >> 8;
        const float4* kp = (const float4*)(kx + (b * HWT + tt) * DIMC + hh * HDX) + half * 4;
        const float4* qp = (const float4*)(&qxs[rr][hh * HDX]) + half * 4;
        float a = 0.f;
        #pragma unroll
        for (int d4 = 0; d4 < 4; ++d4) {
            float4 k4 = kp[d4], q4 = qp[d4];
            a = fmaf(q4.x, k4.x, a); a = fmaf(q4.y, k4.y, a);
            a = fmaf(q4.z, k4.z, a); a = fmaf(q4.w, k4.w, a);
        }
        a += __shfl_xor(a, 1, 64);
        if (half == 0) lg[rr][hh * 16 + tt] = a * 0.17677669529663689f;
    }
    __syncthreads();
    if (t < 16) {
        int rr = t >> 3, hh = t & 7;
        float m = -1e30f;
        for (int tt = 0; tt < 16; ++tt) m = fmaxf(m, lg[rr][hh * 16 + tt]);
        float s = 0.f;
        for (int tt = 0; tt < 16; ++tt) {
            float e = __expf(lg[rr][hh * 16 + tt] - m);
            psm[rr][hh * 16 + tt] = e; s += e;
        }
        float rs = 1.f / s;
        for (int tt = 0; tt < 16; ++tt) psm[rr][hh * 16 + tt] *= rs;
    }
    __syncthreads();
    {
        int hh = c >> 5;
        const float* vp = vx + b * HWT * DIMC + c;
        float a = 0.f;
        #pragma unroll
        for (int tt = 0; tt < 16; ++tt)
            a = fmaf(psm[r][hh * 16 + tt], vp[tt * DIMC], a);
        ctx[r][c] = a;
    }
    __syncthreads();
    {
        int h = r;
        float bm = (h == 0) ? mob[c] : 0.f;
        float a0 = bm, a1 = bm;
        int dbase = h * 128;
        #pragma unroll 4
        for (int d4 = 0; d4 < 32; ++d4) {
            int d = dbase + d4 * 4;
            float w0 = mowT[(d + 0) * DIMC + c];
            float w1 = mowT[(d + 1) * DIMC + c];
            float w2 = mowT[(d + 2) * DIMC + c];
            float w3 = mowT[(d + 3) * DIMC + c];
            float4 c0 = *(const float4*)&ctx[0][d];
            float4 c1 = *(const float4*)&ctx[1][d];
            a0 = fmaf(w0, c0.x, a0); a0 = fmaf(w1, c0.y, a0); a0 = fmaf(w2, c0.z, a0); a0 = fmaf(w3, c0.w, a0);
            a1 = fmaf(w0, c1.x, a1); a1 = fmaf(w1, c1.y, a1); a1 = fmaf(w2, c1.z, a1); a1 = fmaf(w3, c1.w, a1);
        }
        part[h][0][c] = a0; part[h][1][c] = a1;
    }
    __syncthreads();
    x2[r][c] = pf + part[0][r][c] + part[1][r][c];
    __syncthreads();
    {
        int ch = t;
        int g = ch >> 6;
        float aq0 = 0.f, aq1 = 0.f;
        #pragma unroll
        for (int ci = 0; ci < 32; ++ci) {
            float w = qwT[ci * INNER + ch];
            aq0 = fmaf(w, x2[0][g * 32 + ci], aq0);
            aq1 = fmaf(w, x2[1][g * 32 + ci], aq1);
        }
        qls[0][ch] = aq0; qls[1][ch] = aq1;
        qT[(b * NQ + n0 + 0) * INNER + ch] = aq0;
        qT[(b * NQ + n0 + 1) * INNER + ch] = aq1;
    }
    __syncthreads();
    if (t < 256) {
        int pr = t >> 4, l = t & 15;
        int rr = pr >> 3, g = pr & 7;
        float s0 = 0.f, s1 = 0.f;
        #pragma unroll
        for (int e = 0; e < 4; ++e) {
            int jj = l * 4 + e;
            float ev = gelu_exact(fmaf(qls[rr][g * 64 + jj], off_w1[jj], off_b1[jj]));
            s0 = fmaf(ev, off_w2[jj], s0);
            s1 = fmaf(ev, off_w2[64 + jj], s1);
        }
        #pragma unroll
        for (int o = 8; o > 0; o >>= 1) {
            s0 += __shfl_xor(s0, o, 64);
            s1 += __shfl_xor(s1, o, 64);
        }
        if (l == 0) {
            float vgx = g01[rr][0] + tanhf(s0) * (2.f / 3.f);
            float vgy = g01[rr][1] + tanhf(s1) * (2.f / 3.f);
            vg[rr][g][0] = vgx; vg[rr][g][1] = vgy;
            float* vp = vgrid_g + ((b * GROUPS + g) * NQ + n0 + rr) * 2;
            vp[0] = vgx; vp[1] = vgy;
        }
    }
    __syncthreads();
    {
        int g = c >> 5;
        float x = (vg[r][g][0] + 1.f) * 2.f - 0.5f;
        float y = (vg[r][g][1] + 1.f) * 2.f - 0.5f;
        float x0f = floorf(x), y0f = floorf(y);
        float wx = x - x0f, wy = y - y0f;
        int x0 = (int)x0f, y0 = (int)y0f;
        const float* img = rgb + (b * DIMC + c) * HWT;
        float v00 = samp4(img, y0, x0), v01 = samp4(img, y0, x0 + 1);
        float v10 = samp4(img, y0 + 1, x0), v11 = samp4(img, y0 + 1, x0 + 1);
        kvs[r][c] = v00 * (1.f - wx) * (1.f - wy) + v01 * wx * (1.f - wy)
                  + v10 * (1.f - wx) * wy + v11 * wx * wy;
    }
    __syncthreads();
    {
        int ch = t;
        int g = ch >> 6;
        float ak0 = 0.f, ak1 = 0.f, av0 = 0.f, av1 = 0.f;
        #pragma unroll
        for (int ci = 0; ci < 32; ++ci) {
            float wk = kwT[ci * INNER + ch];
            float wv = vwT[ci * INNER + ch];
            float x0 = kvs[0][g * 32 + ci];
            float x1 = kvs[1][g * 32 + ci];
            ak0 = fmaf(wk, x0, ak0); ak1 = fmaf(wk, x1, ak1);
            av0 = fmaf(wv, x0, av0); av1 = fmaf(wv, x1, av1);
        }
        int hh = ch >> 6, dh = ch & 63;
        float2 kk; kk.x = ak0; kk.y = ak1;
        *(float2*)(kTt + ((b * HEADS + hh) * DH + dh) * NQ + n0) = kk;
        vT[(b * NQ + n0 + 0) * INNER + ch] = av0;
        vT[(b * NQ + n0 + 1) * INNER + ch] = av1;
    }
}

// ---------------- K3b: sim + table-bias + softmax + attn@V ----------------
__global__ __launch_bounds__(256) void k3b_attn(
        const float* __restrict__ qT, const float* __restrict__ kTt,
        const float* __restrict__ vT, const float* __restrict__ tab,
        const float* __restrict__ pose_init, const float* __restrict__ vgrid_g,
        float* __restrict__ aoT) {
    int bg = blockIdx.x >> 5;
    int itile = blockIdx.x & 31;
    int b = bg >> 3, h = bg & 7;
    int i0 = itile * 8;
    int tid = threadIdx.x;

    __shared__ __align__(16) float q_s[8][64];
    __shared__ __align__(16) float attn_s[8][NQ];
    __shared__ __align__(16) float vstage[64][64];
    __shared__ float2 vg_s[NQ];
    __shared__ float2 gi_s[8];
    __shared__ float ssum_s[8];

    for (int idx = tid; idx < 8 * 64; idx += 256) {
        int i = idx >> 6, d = idx & 63;
        q_s[i][d] = qT[(b * NQ + i0 + i) * INNER + h * 64 + d] * 0.125f;
    }
    if (tid < NQ) vg_s[tid] = ((const float2*)vgrid_g)[bg * NQ + tid];
    if (tid >= 240 && tid < 248) {
        int i = tid - 240;
        float2 g;
        g.x = 2.f * pose_init[(b * 2 + 0) * NQ + i0 + i] - 1.f;
        g.y = 2.f * pose_init[(b * 2 + 1) * NQ + i0 + i] - 1.f;
        gi_s[i] = g;
    }
    __syncthreads();

    {
        int jq = tid & 63, ih = tid >> 6;
        float2 gi0 = gi_s[ih], gi1 = gi_s[ih + 4];
        float2 vg0 = vg_s[jq * 4 + 0];
        float2 vg1 = vg_s[jq * 4 + 1];
        float2 vg2 = vg_s[jq * 4 + 2];
        float2 vg3 = vg_s[jq * 4 + 3];
        float b00 = tab_lookup(tab, gi0.x - vg0.x, gi0.y - vg0.y);
        float b01 = tab_lookup(tab, gi0.x - vg1.x, gi0.y - vg1.y);
        float b02 = tab_lookup(tab, gi0.x - vg2.x, gi0.y - vg2.y);
        float b03 = tab_lookup(tab, gi0.x - vg3.x, gi0.y - vg3.y);
        float b10 = tab_lookup(tab, gi1.x - vg0.x, gi1.y - vg0.y);
        float b11 = tab_lookup(tab, gi1.x - vg1.x, gi1.y - vg1.y);
        float b12 = tab_lookup(tab, gi1.x - vg2.x, gi1.y - vg2.y);
        float b13 = tab_lookup(tab, gi1.x - vg3.x, gi1.y - vg3.y);

        const float4* kb4 = (const float4*)(kTt + bg * DH * NQ) + jq;
        float4 s0 = {b00, b01, b02, b03};
        float4 s1 = {b10, b11, b12, b13};
        #pragma unroll 8
        for (int d = 0; d < 64; ++d) {
            float4 kv = kb4[d * 64];
            float q0 = q_s[ih][d], q1 = q_s[ih + 4][d];
            s0.x = fmaf(q0, kv.x, s0.x); s0.y = fmaf(q0, kv.y, s0.y);
            s0.z = fmaf(q0, kv.z, s0.z); s0.w = fmaf(q0, kv.w, s0.w);
            s1.x = fmaf(q1, kv.x, s1.x); s1.y = fmaf(q1, kv.y, s1.y);
            s1.z = fmaf(q1, kv.z, s1.z); s1.w = fmaf(q1, kv.w, s1.w);
        }
        *(float4*)&attn_s[ih][jq * 4] = s0;
        *(float4*)&attn_s[ih + 4][jq * 4] = s1;
    }
    __syncthreads();
    {
        int il = tid >> 5, lane = tid & 31;
        float m = -1e30f;
        for (int jj = 0; jj < 8; ++jj) m = fmaxf(m, attn_s[il][jj * 32 + lane]);
        #pragma unroll
        for (int o = 16; o > 0; o >>= 1) m = fmaxf(m, __shfl_xor(m, o, 32));
        float s = 0.f;
        for (int jj = 0; jj < 8; ++jj) {
            int j = jj * 32 + lane;
            float e = __expf(attn_s[il][j] - m);
            attn_s[il][j] = e;
            s += e;
        }
        #pragma unroll
        for (int o = 16; o > 0; o >>= 1) s += __shfl_xor(s, o, 32);
        if (lane == 0) ssum_s[il] = s;
    }
    // ---- PV over 4 LDS-staged chunks of 64 j ----
    {
        int lane = tid & 31, il = tid >> 5;
        float a0 = 0.f, a1 = 0.f, c0 = 0.f, c1 = 0.f;
        #pragma unroll 1
        for (int jc = 0; jc < 4; ++jc) {
            __syncthreads();
            #pragma unroll
            for (int rep = 0; rep < 4; ++rep) {
                int idx = rep * 256 + tid;
                int row = idx >> 4, c4 = idx & 15;
                float4 v = *(const float4*)(vT + (b * NQ + jc * 64 + row) * INNER + h * 64 + c4 * 4);
                *(float4*)&vstage[row][c4 * 4] = v;
            }
            __syncthreads();
            const float* ar = &attn_s[il][jc * 64];
            #pragma unroll 8
            for (int j = 0; j < 64; j += 2) {
                float w0 = ar[j], w1 = ar[j + 1];
                float2 v0 = *(const float2*)&vstage[j][lane * 2];
                float2 v1 = *(const float2*)&vstage[j + 1][lane * 2];
                a0 = fmaf(w0, v0.x, a0); a1 = fmaf(w0, v0.y, a1);
                c0 = fmaf(w1, v1.x, c0); c1 = fmaf(w1, v1.y, c1);
            }
        }
        float r = 1.f / ssum_s[il];
        float2 res; res.x = (a0 + c0) * r; res.y = (a1 + c1) * r;
        *(float2*)(aoT + (b * NQ + i0 + il) * INNER + h * 64 + lane * 2) = res;
    }
}

// ---------------- K4: final projection 512 -> 256 (coalesced owT) ----------------
__global__ __launch_bounds__(256) void k4_proj(const float* __restrict__ aoT,
        const float* __restrict__ owT, const float* __restrict__ out_b,
        float* __restrict__ out) {
    int b = blockIdx.x >> 6;
    int n0 = (blockIdx.x & 63) * 4;
    int t = threadIdx.x;
    __shared__ __align__(16) float xl[4][INNER];
    for (int idx = t; idx < 4 * INNER; idx += 256) {
        xl[idx >> 9][idx & 511] = aoT[(b * NQ + n0) * INNER + idx];
    }
    __syncthreads();
    float bo = out_b[t];
    float a0 = bo, a1 = bo, a2 = bo, a3 = bo;
    #pragma unroll 2
    for (int c4 = 0; c4 < 128; ++c4) {
        int c = c4 * 4;
        float w0 = owT[(c + 0) * DIMC + t];
        float w1 = owT[(c + 1) * DIMC + t];
        float w2 = owT[(c + 2) * DIMC + t];
        float w3 = owT[(c + 3) * DIMC + t];
        float4 x0 = *(const float4*)&xl[0][c];
        float4 x1 = *(const float4*)&xl[1][c];
        float4 x2 = *(const float4*)&xl[2][c];
        float4 x3 = *(const float4*)&xl[3][c];
        a0 = fmaf(w0, x0.x, a0); a0 = fmaf(w1, x0.y, a0); a0 = fmaf(w2, x0.z, a0); a0 = fmaf(w3, x0.w, a0);
        a1 = fmaf(w0, x1.x, a1); a1 = fmaf(w1, x1.y, a1); a1 = fmaf(w2, x1.z, a1); a1 = fmaf(w3, x1.w, a1);
        a2 = fmaf(w0, x2.x, a2); a2 = fmaf(w1, x2.y, a2); a2 = fmaf(w2, x2.z, a2); a2 = fmaf(w3, x2.w, a2);
        a3 = fmaf(w0, x3.x, a3); a3 = fmaf(w1, x3.y, a3); a3 = fmaf(w2, x3.z, a3); a3 = fmaf(w3, x3.w, a3);
    }
    float4 res; res.x = a0; res.y = a1; res.z = a2; res.w = a3;
    *(float4*)(out + (b * DIMC + t) * NQ + n0) = res;
}

extern "C" void kernel_launch(void* const* d_in, const int* in_sizes, int n_in,
                              void* d_out, int out_size, void* d_ws, size_t ws_size,
                              hipStream_t stream) {
    const float* pose_feat = (const float*)d_in[0];
    const float* rgb       = (const float*)d_in[1];
    const float* pose_init = (const float*)d_in[2];
    const float* mha_in_w  = (const float*)d_in[3];
    const float* mha_in_b  = (const float*)d_in[4];
    const float* mha_out_w = (const float*)d_in[5];
    const float* mha_out_b = (const float*)d_in[6];
    const float* pe_gauss  = (const float*)d_in[7];
    const float* off_w1    = (const float*)d_in[8];
    const float* off_b1    = (const float*)d_in[9];
    const float* off_w2    = (const float*)d_in[10];
    const float* cpb_w0    = (const float*)d_in[11];
    const float* cpb_b0    = (const float*)d_in[12];
    const float* cpb_w1    = (const float*)d_in[13];
    const float* cpb_b1    = (const float*)d_in[14];
    const float* cpb_w2    = (const float*)d_in[15];
    const float* cpb_b2    = (const float*)d_in[16];
    const float* q_w       = (const float*)d_in[17];
    const float* k_w       = (const float*)d_in[18];
    const float* v_w       = (const float*)d_in[19];
    const float* out_w     = (const float*)d_in[20];
    const float* out_b     = (const float*)d_in[21];

    float* ws    = (float*)d_ws;
    float* kx    = ws;                     // 16384
    float* vx    = kx + 16384;             // 16384
    float* qT    = vx + 16384;             // 524288
    float* kTt   = qT + 524288;            // 524288
    float* vT    = kTt + 524288;           // 524288
    float* vgrid = vT + 524288;            // 16384
    float* aoT   = vgrid + 16384;          // 524288
    float* WqT   = aoT + 524288;           // 65536
    float* mowT  = WqT + 65536;            // 65536
    float* owT   = mowT + 65536;           // 131072
    float* qwT   = owT + 131072;           // 16384
    float* kwT   = qwT + 16384;            // 16384
    float* vwT   = kwT + 16384;            // 16384
    float* tab   = vwT + 16384;            // 65536 (256 KB table)
    float* out   = (float*)d_out;

    kprep<<<664, 256, 0, stream>>>(mha_in_w, mha_out_w, out_w, q_w, k_w, v_w,
        cpb_w0, cpb_b0, cpb_b1, cpb_w1, cpb_w2, cpb_b2, rgb, mha_in_b,
        WqT, mowT, owT, qwT, kwT, vwT, tab, kx, vx);
    k2_qkv<<<512, 512, 0, stream>>>(pose_feat, rgb, pose_init, mha_in_b,
        WqT, mowT, mha_out_b, pe_gauss, off_w1, off_b1, off_w2, qwT, kwT, vwT,
        kx, vx, qT, kTt, vT, vgrid);
    k3b_attn<<<1024, 256, 0, stream>>>(qT, kTt, vT, tab, pose_init, vgrid, aoT);
    k4_proj<<<256, 256, 0, stream>>>(aoT, owT, out_b, out);
}